// Round 1
// baseline (987.666 us; speedup 1.0000x reference)
//
#include <hip/hip_runtime.h>

typedef unsigned short u16;
typedef unsigned int u32;
typedef __attribute__((ext_vector_type(8))) short bf16x8;
typedef __attribute__((ext_vector_type(4))) float f32x4;

// Problem constants
#define CB 2
#define CT 2048
#define CD 2048
#define CN 1024
#define CH 16
#define CR 512
#define CDH 128

__device__ __forceinline__ float b2f(u16 u) {
  union { u32 i; float f; } v; v.i = ((u32)u) << 16; return v.f;
}
__device__ __forceinline__ u16 f2b(float f) {
  u32 u = __builtin_bit_cast(u32, f);
  u32 r = u + 0x7FFFu + ((u >> 16) & 1u);
  return (u16)(r >> 16);
}
__device__ __forceinline__ u16 f2h(float f) {
  return __builtin_bit_cast(u16, (_Float16)f);
}
__device__ __forceinline__ float h2f(u16 u) {
  return (float)__builtin_bit_cast(_Float16, u);
}
__device__ __forceinline__ float wsum(float v) {
  #pragma unroll
  for (int o = 32; o; o >>= 1) v += __shfl_xor(v, o);
  return v;
}
__device__ __forceinline__ float wmax(float v) {
  #pragma unroll
  for (int o = 32; o; o >>= 1) v = fmaxf(v, __shfl_xor(v, o));
  return v;
}

// ---------- dtype detector: flag=0 bf16 storage, flag=1 fp32 storage ----------
__global__ void k_detect(const u32* x, int* flag) {
  int lane = threadIdx.x;
  u32 w = x[lane * 131 + 7];
  float v = b2f((u16)(w & 0xFFFF));
  float a = fabsf(v);
  bool sane = (a > 1e-3f) && (a < 100.0f);
  unsigned long long m = __ballot(sane);
  if (lane == 0) flag[0] = (__popcll(m) >= 32) ? 0 : 1;
}

// ---------- canonicalize small weight arrays to bf16 in ws ----------
struct ConvArgs {
  const void* src[11];
  unsigned cnt[11];
  unsigned dst[11];
};
__global__ void k_conv(ConvArgs a, u16* wb, const int* flag) {
  int dt = flag[0];
  unsigned stride = gridDim.x * blockDim.x;
  unsigned tid0 = blockIdx.x * blockDim.x + threadIdx.x;
  #pragma unroll 1
  for (int s = 0; s < 11; ++s) {
    const void* sp = a.src[s];
    u16* d = wb + a.dst[s];
    unsigned c = a.cnt[s];
    for (unsigned i = tid0; i < c; i += stride)
      d[i] = dt ? f2b(((const float*)sp)[i]) : ((const u16*)sp)[i];
  }
}

// ---------- generic bf16 MFMA GEMM: C[M,N] = A[M,K] * B[K,N] ----------
// A may be bf16 or fp32 (a_dyn && flag). C stored bf16, or fp32 if (out_dyn && flag).
__global__ __launch_bounds__(256)
void k_gemm(const void* A, const u16* Bw, void* C, int Mg, int Ng, int Kg,
            const int* flag, int a_dyn, int out_dyn) {
  __shared__ u16 As[64][40];
  __shared__ u16 Bs[64][40];
  int tid = threadIdx.x;
  int wave = tid >> 6, lane = tid & 63, quad = lane >> 4, l16 = lane & 15;
  int m0 = blockIdx.y * 64, n0 = blockIdx.x * 64;
  int dt = flag[0];
  bool a32 = a_dyn && dt;
  bool o32 = out_dyn && dt;

  int ar = tid >> 2, ak = (tid & 3) * 8;
  int bk = tid >> 3, bn = (tid & 7) * 8;

  f32x4 acc[4] = {};

  for (int k0 = 0; k0 < Kg; k0 += 32) {
    size_t ea = (size_t)(m0 + ar) * Kg + k0 + ak;
    if (!a32) {
      *(uint4*)&As[ar][ak] = *(const uint4*)((const u16*)A + ea);
    } else {
      const float* Af = (const float*)A + ea;
      float4 v0 = *(const float4*)Af;
      float4 v1 = *(const float4*)(Af + 4);
      As[ar][ak+0]=f2b(v0.x); As[ar][ak+1]=f2b(v0.y); As[ar][ak+2]=f2b(v0.z); As[ar][ak+3]=f2b(v0.w);
      As[ar][ak+4]=f2b(v1.x); As[ar][ak+5]=f2b(v1.y); As[ar][ak+6]=f2b(v1.z); As[ar][ak+7]=f2b(v1.w);
    }
    uint4 bv = *(const uint4*)&Bw[(size_t)(k0 + bk) * Ng + n0 + bn];
    const u16* bp = (const u16*)&bv;
    #pragma unroll
    for (int i = 0; i < 8; ++i) Bs[bn + i][bk] = bp[i];
    __syncthreads();
    bf16x8 af = *(const bf16x8*)&As[wave*16 + l16][quad*8];
    #pragma unroll
    for (int j = 0; j < 4; ++j) {
      bf16x8 bfj = *(const bf16x8*)&Bs[j*16 + l16][quad*8];
      acc[j] = __builtin_amdgcn_mfma_f32_16x16x32_bf16(af, bfj, acc[j], 0, 0, 0);
    }
    __syncthreads();
  }
  int mrow = m0 + wave*16 + quad*4;
  #pragma unroll
  for (int j = 0; j < 4; ++j) {
    #pragma unroll
    for (int r = 0; r < 4; ++r) {
      size_t ci = (size_t)(mrow + r) * Ng + n0 + j*16 + l16;
      float v = acc[j][r];
      if (o32) ((float*)C)[ci] = v;
      else ((u16*)C)[ci] = f2b(v);
    }
  }
}

// ---------- q post: RMSNorm + RoPE + relayout (B,T,H,DH) -> (B,H,T,DH) ----------
__global__ __launch_bounds__(64)
void k_qpost(const u16* qraw, const u16* qw, const int* tok, u16* qT) {
  int bid = blockIdx.x;
  int h = bid & 15, bt = bid >> 4;
  int t = bt & (CT - 1), b = bt >> 11;
  int lane = threadIdx.x;
  size_t base = (size_t)bt * CD + h * CDH;
  float x0 = b2f(qraw[base + lane]);
  float x1 = b2f(qraw[base + lane + 64]);
  float ss = wsum(x0*x0 + x1*x1);
  float inv = rsqrtf(ss * (1.0f/128.0f) + 1e-6f);
  float y0 = x0 * inv * b2f(qw[lane]);
  float y1 = x1 * inv * b2f(qw[lane + 64]);
  float pos = (float)(tok[0] + t);
  float invf = __expf(-(float)lane * (9.210340371976184f / 64.0f));
  float sn, cs; sincosf(pos * invf, &sn, &cs);
  float o0 = y0*cs - y1*sn;
  float o1 = y1*cs + y0*sn;
  size_t ob = ((size_t)(b*CH + h) * CT + t) * CDH;
  qT[ob + lane] = f2b(o0);
  qT[ob + lane + 64] = f2b(o1);
}

// ---------- k/v post: k RMSNorm+RoPE, v copy; relayout (B,N,H,DH)->(B,H,N,DH) ----------
__global__ __launch_bounds__(64)
void k_kvpost(const u16* kraw, const u16* vraw, const u16* kw, const int* spos,
              u16* kT, u16* vT) {
  int row = blockIdx.x;
  int h = row & 15, bn = row >> 4;
  int n = bn & (CN - 1), b = bn >> 10;
  int lane = threadIdx.x;
  size_t base = (size_t)row * CDH;
  float x0 = b2f(kraw[base + lane]);
  float x1 = b2f(kraw[base + lane + 64]);
  float ss = wsum(x0*x0 + x1*x1);
  float inv = rsqrtf(ss * (1.0f/128.0f) + 1e-6f);
  float y0 = x0 * inv * b2f(kw[lane]);
  float y1 = x1 * inv * b2f(kw[lane + 64]);
  float pos = (float)spos[n];
  float invf = __expf(-(float)lane * (9.210340371976184f / 64.0f));
  float sn, cs; sincosf(pos * invf, &sn, &cs);
  float o0 = y0*cs - y1*sn;
  float o1 = y1*cs + y0*sn;
  size_t ob = ((size_t)(b*CH + h) * CN + n) * CDH;
  kT[ob + lane] = f2b(o0);
  kT[ob + lane + 64] = f2b(o1);
  vT[ob + lane] = vraw[base + lane];
  vT[ob + lane + 64] = vraw[base + lane + 64];
}

// ---------- fused attention: scores (MFMA) -> top-64 threshold -> softmax+sink -> PV -> gate ----------
#define SELCAP 128
__global__ __launch_bounds__(256)
void k_attn(const u16* qT, const u16* kT, const u16* vT, const u16* graw,
            const int* spos, const int* tok, const u16* sink, u16* o) {
  __shared__ u16 sc[16][1024];      // f16 scores, 32KB
  __shared__ u16 Qt[16][128];       // 4KB
  __shared__ int pos_s[1024];       // 4KB
  __shared__ int sel_n[4][SELCAP];
  __shared__ float sel_e[4][SELCAP];
  __shared__ int sel_c[4];

  int tid = threadIdx.x;
  int wave = tid >> 6, lane = tid & 63, quad = lane >> 4, l16 = lane & 15;
  int bid = blockIdx.x;
  int tile = bid & 127, bh = bid >> 7;
  int h = bh & 15, b = bh >> 4;
  int t0 = tile * 16;
  const u16* qb = qT + ((size_t)bh * CT + t0) * CDH;
  const u16* kb = kT + (size_t)bh * CN * CDH;
  const u16* vb = vT + (size_t)bh * CN * CDH;

  ((uint4*)&Qt[0][0])[tid] = ((const uint4*)qb)[tid];   // 256 * 8 u16 = 2048
  ((int4*)pos_s)[tid] = ((const int4*)spos)[tid & 255]; // 256 int4 = 1024 ints (dup writes ok)
  __syncthreads();

  bf16x8 af[4];
  #pragma unroll
  for (int ks = 0; ks < 4; ++ks) af[ks] = *(const bf16x8*)&Qt[l16][ks*32 + quad*8];
  int tok0 = tok[0];

  // score phase: each wave does 16x16 tiles over n
  for (int p = 0; p < 16; ++p) {
    int n0 = p*64 + wave*16;
    f32x4 c = {};
    const u16* krow = &kb[(size_t)(n0 + l16) * CDH];
    #pragma unroll
    for (int ks = 0; ks < 4; ++ks) {
      bf16x8 bfr = *(const bf16x8*)&krow[ks*32 + quad*8];
      c = __builtin_amdgcn_mfma_f32_16x16x32_bf16(af[ks], bfr, c, 0, 0, 0);
    }
    int n = n0 + l16;
    int pn = pos_s[n];
    #pragma unroll
    for (int r = 0; r < 4; ++r) {
      int t = quad*4 + r;
      float s = c[r] * 0.08838834764831845f;
      if (pn >= tok0 + t0 + t) s = -INFINITY;
      sc[t][n] = f2h(s);
    }
  }
  __syncthreads();

  float sinkv = b2f(sink[h]);

  // per-t phase: wave w handles t = w*4 + s5
  for (int s5 = 0; s5 < 4; ++s5) {
    int tl = wave*4 + s5;
    int t = t0 + tl;
    if (lane == 0) sel_c[wave] = 0;
    __syncthreads();

    float sv[16]; int key[16];
    float mx = -INFINITY;
    #pragma unroll
    for (int j = 0; j < 16; ++j) {
      float f = h2f(sc[tl][lane + (j << 6)]);
      sv[j] = f; mx = fmaxf(mx, f);
      float fs = fminf(fmaxf(f * 256.0f + 2048.0f, 0.0f), 4095.0f);
      key[j] = (int)fs;
    }
    mx = wmax(mx);

    // binary search on fixed-point keys for the 64th-largest value (matches "scores >= kth")
    int lo = 0, hi = 4096;
    #pragma unroll 1
    for (int it = 0; it < 12; ++it) {
      int mid = (lo + hi) >> 1;
      int cnt = 0;
      #pragma unroll
      for (int j = 0; j < 16; ++j) cnt += (int)__popcll(__ballot(key[j] >= mid));
      if (cnt >= 64) lo = mid; else hi = mid;
    }

    float m = fmaxf(mx, sinkv);
    float zp = 0.f;
    #pragma unroll 1
    for (int j = 0; j < 16; ++j) {
      if (key[j] >= lo && sv[j] > -1e37f) {
        float e = __expf(sv[j] - m);
        int slot = atomicAdd(&sel_c[wave], 1);
        if (slot < SELCAP) { sel_n[wave][slot] = lane + (j << 6); sel_e[wave][slot] = e; zp += e; }
      }
    }
    float Z = wsum(zp) + __expf(sinkv - m);
    __syncthreads();

    int cnt = min(sel_c[wave], SELCAP);
    float a0 = 0.f, a1 = 0.f;
    #pragma unroll 1
    for (int i = 0; i < cnt; ++i) {
      int n = sel_n[wave][i];
      float e = sel_e[wave][i];
      u32 pv = *(const u32*)&vb[(size_t)n * CDH + 2*lane];
      a0 += e * b2f((u16)(pv & 0xFFFF));
      a1 += e * b2f((u16)(pv >> 16));
    }
    float rz = 1.0f / Z;
    size_t oi = ((size_t)(b*CT + t)) * CD + h*CDH + 2*lane;
    u32 pg = *(const u32*)&graw[oi];
    float g0 = 1.0f / (1.0f + __expf(-b2f((u16)(pg & 0xFFFF))));
    float g1 = 1.0f / (1.0f + __expf(-b2f((u16)(pg >> 16))));
    float r0 = a0 * rz * g0;
    float r1 = a1 * rz * g1;
    *(u32*)&o[oi] = (u32)f2b(r0) | ((u32)f2b(r1) << 16);
  }
}

extern "C" void kernel_launch(void* const* d_in, const int* in_sizes, int n_in,
                              void* d_out, int out_size, void* d_ws, size_t ws_size,
                              hipStream_t stream) {
  char* ws = (char*)d_ws;
  int* flag = (int*)(ws + 0);
  u16* wb = (u16*)(ws + 256);

  // canonical weight arrays (elem offsets in wb)
  const unsigned CNTS[11] = {262144,262144,262144,262144,262144,262144,65536,65536,128,128,16};
  const int MAP[11] = {4,5,6,7,8,9,10,11,12,13,14};
  ConvArgs ca;
  unsigned off = 0, offs[11];
  for (int i = 0; i < 11; ++i) {
    ca.src[i] = d_in[MAP[i]];
    ca.cnt[i] = CNTS[i];
    offs[i] = off; ca.dst[i] = off;
    off += (CNTS[i] + 127u) & ~127u;
  }
  u16* cWqd = wb + offs[0];
  u16* cWqu = wb + offs[1];
  u16* cWgd = wb + offs[2];
  u16* cWgu = wb + offs[3];
  u16* cWod = wb + offs[4];
  u16* cWou = wb + offs[5];
  u16* cWk  = wb + offs[6];
  u16* cWv  = wb + offs[7];
  u16* cqw  = wb + offs[8];
  u16* ckw  = wb + offs[9];
  u16* csink= wb + offs[10];

  // intermediate buffers (bytes from ws base)
  const size_t O_QLAT = 4194304;                    // 1MB
  const size_t O_GLAT = O_QLAT + 1048576;           // 1MB
  const size_t O_QRAW = O_GLAT + 1048576;           // 16.78MB (later aliased as attention output 'o')
  const size_t O_GRAW = O_QRAW + 16777216;          // 16.78MB
  const size_t O_KRAW = O_GRAW + 16777216;          // 8.39MB (later aliased as o_lat)
  const size_t O_VRAW = O_KRAW + 8388608;           // 8.39MB
  const size_t O_QT   = O_VRAW + 8388608;           // 16.78MB
  const size_t O_KT   = O_QT   + 16777216;          // 8.39MB
  const size_t O_VT   = O_KT   + 8388608;           // 8.39MB

  const int* spos = (const int*)d_in[2];
  const int* tok  = (const int*)d_in[3];

  k_detect<<<1, 64, 0, stream>>>((const u32*)d_in[0], flag);
  k_conv<<<256, 256, 0, stream>>>(ca, wb, flag);

  // q_lat = x @ Wq_down ; g_lat = x @ Wg_down
  k_gemm<<<dim3(2,64), 256, 0, stream>>>(d_in[0], cWqd, ws + O_QLAT, 4096, 128, 2048, flag, 1, 0);
  k_gemm<<<dim3(2,64), 256, 0, stream>>>(d_in[0], cWgd, ws + O_GLAT, 4096, 128, 2048, flag, 1, 0);
  // qraw = q_lat @ Wq_up ; graw = g_lat @ Wg_up
  k_gemm<<<dim3(32,64), 256, 0, stream>>>(ws + O_QLAT, cWqu, ws + O_QRAW, 4096, 2048, 128, flag, 0, 0);
  k_gemm<<<dim3(32,64), 256, 0, stream>>>(ws + O_GLAT, cWgu, ws + O_GRAW, 4096, 2048, 128, flag, 0, 0);
  // kraw = snap @ Wk_up ; vraw = snap @ Wv_up   (rows = B*N*H, K = R)
  k_gemm<<<dim3(2,512), 256, 0, stream>>>(d_in[1], cWk, ws + O_KRAW, 32768, 128, 512, flag, 1, 0);
  k_gemm<<<dim3(2,512), 256, 0, stream>>>(d_in[1], cWv, ws + O_VRAW, 32768, 128, 512, flag, 1, 0);

  k_qpost<<<65536, 64, 0, stream>>>((const u16*)(ws + O_QRAW), cqw, tok, (u16*)(ws + O_QT));
  k_kvpost<<<32768, 64, 0, stream>>>((const u16*)(ws + O_KRAW), (const u16*)(ws + O_VRAW),
                                     ckw, spos, (u16*)(ws + O_KT), (u16*)(ws + O_VT));

  // attention writes 'o' into the (dead) QRAW region
  k_attn<<<4096, 256, 0, stream>>>((const u16*)(ws + O_QT), (const u16*)(ws + O_KT),
                                   (const u16*)(ws + O_VT), (const u16*)(ws + O_GRAW),
                                   spos, tok, csink, (u16*)(ws + O_QRAW));

  // o_lat = o @ Wo_down (into dead KRAW region) ; out = o_lat @ Wo_up
  k_gemm<<<dim3(2,64), 256, 0, stream>>>(ws + O_QRAW, cWod, ws + O_KRAW, 4096, 128, 2048, flag, 0, 0);
  k_gemm<<<dim3(32,64), 256, 0, stream>>>(ws + O_KRAW, cWou, d_out, 4096, 2048, 128, flag, 0, 1);
}

// Round 2
// 822.305 us; speedup vs baseline: 1.2011x; 1.2011x over previous
//
#include <hip/hip_runtime.h>

typedef unsigned short u16;
typedef unsigned int u32;
typedef __attribute__((ext_vector_type(8))) short bf16x8;
typedef __attribute__((ext_vector_type(8))) _Float16 f16x8;
typedef __attribute__((ext_vector_type(4))) float f32x4;

__device__ __forceinline__ float b2f(u16 u) {
  union { u32 i; float f; } v; v.i = ((u32)u) << 16; return v.f;
}
__device__ __forceinline__ u16 f2b(float f) {
  u32 u = __builtin_bit_cast(u32, f);
  u32 r = u + 0x7FFFu + ((u >> 16) & 1u);
  return (u16)(r >> 16);
}
__device__ __forceinline__ u16 f2h(float f) {
  return __builtin_bit_cast(u16, (_Float16)f);
}
__device__ __forceinline__ float h2f(u16 u) {
  return (float)__builtin_bit_cast(_Float16, u);
}
__device__ __forceinline__ float wsum(float v) {
  #pragma unroll
  for (int o = 32; o; o >>= 1) v += __shfl_xor(v, o);
  return v;
}
__device__ __forceinline__ int wsumi(int v) {
  #pragma unroll
  for (int o = 32; o; o >>= 1) v += __shfl_xor(v, o);
  return v;
}
__device__ __forceinline__ float wmax(float v) {
  #pragma unroll
  for (int o = 32; o; o >>= 1) v = fmaxf(v, __shfl_xor(v, o));
  return v;
}

// ---------- dtype detector: flag=0 bf16 storage, flag=1 fp32 ----------
__global__ void k_detect(const u32* x, int* flag) {
  int lane = threadIdx.x;
  u32 w = x[lane * 131 + 7];
  float v = b2f((u16)(w & 0xFFFF));
  float a = fabsf(v);
  bool sane = (a > 1e-3f) && (a < 100.0f);
  unsigned long long m = __ballot(sane);
  if (lane == 0) flag[0] = (__popcll(m) >= 32) ? 0 : 1;
}

// ---------- weight transpose+convert: W[K][N] (f32/bf16) -> BT[col][K] bf16 ----------
__global__ __launch_bounds__(256)
void k_wtrans(const void* src, u16* dst, int K, int N, const int* flag) {
  __shared__ u16 Ts[64][66];
  int t = threadIdx.x;
  int col0 = blockIdx.x * 64, k0 = blockIdx.y * 64;
  int dt = flag[0];
  int lr = t >> 4, lc = (t & 15) * 4;
  if (dt) {
    #pragma unroll
    for (int p = 0; p < 4; ++p) {
      int kr = lr + p * 16;
      float4 v = *(const float4*)((const float*)src + (size_t)(k0 + kr) * N + col0 + lc);
      Ts[kr][lc+0] = f2b(v.x); Ts[kr][lc+1] = f2b(v.y);
      Ts[kr][lc+2] = f2b(v.z); Ts[kr][lc+3] = f2b(v.w);
    }
  } else {
    #pragma unroll
    for (int p = 0; p < 4; ++p) {
      int kr = lr + p * 16;
      uint2 v = *(const uint2*)((const u16*)src + (size_t)(k0 + kr) * N + col0 + lc);
      *(uint2*)&Ts[kr][lc] = v;
    }
  }
  __syncthreads();
  int col = t >> 2, ks = (t & 3) * 16;
  u16 tmp[16];
  #pragma unroll
  for (int i = 0; i < 16; ++i) tmp[i] = Ts[ks + i][col];
  u16* dp = dst + (size_t)(col0 + col) * K + k0 + ks;
  *(uint4*)dp = *(uint4*)&tmp[0];
  *(uint4*)(dp + 8) = *(uint4*)&tmp[8];
}

// ---------- small vector convert ----------
__global__ void k_vecconv(const void* qw, const void* kw, const void* sk,
                          u16* dq, u16* dk, u16* dsnk, const int* flag) {
  int t = threadIdx.x; int dt = flag[0];
  if (t < 128) dq[t] = dt ? f2b(((const float*)qw)[t]) : ((const u16*)qw)[t];
  else if (t < 256) dk[t-128] = dt ? f2b(((const float*)kw)[t-128]) : ((const u16*)kw)[t-128];
  if (t < 16) dsnk[t] = dt ? f2b(((const float*)sk)[t]) : ((const u16*)sk)[t];
}

// ---------- skinny GEMM: C[M][N] = A[M][K] * B, BT[N][K] given; tile M=16, full N ----------
// JW = j-tiles per wave (N = JW*64). A fp32 if (ADYN && flag).
template<int JW, int ADYN>
__global__ __launch_bounds__(256)
void k_gemm_skinny(const void* A, const u16* BT, u16* C, int K, int ldc, const int* flag) {
  __shared__ u16 As[16][40];
  int tid = threadIdx.x, wave = tid >> 6, lane = tid & 63, quad = lane >> 4, l16 = lane & 15;
  int m0 = blockIdx.x * 16;
  bool a32 = ADYN && flag[0];
  f32x4 acc[JW];
  #pragma unroll
  for (int j = 0; j < JW; ++j) acc[j] = (f32x4){0.f,0.f,0.f,0.f};

  int row32 = tid >> 4, kp32 = (tid & 15) * 2;
  int row16 = tid >> 2, kp16 = (tid & 3) * 8;
  float2 pf32 = {};
  uint4 pf16 = {};
  if (a32) pf32 = *(const float2*)((const float*)A + (size_t)(m0+row32)*K + kp32);
  else if (tid < 64) pf16 = *(const uint4*)((const u16*)A + (size_t)(m0+row16)*K + kp16);

  for (int k0 = 0; k0 < K; k0 += 32) {
    if (a32) { As[row32][kp32] = f2b(pf32.x); As[row32][kp32+1] = f2b(pf32.y); }
    else if (tid < 64) *(uint4*)&As[row16][kp16] = pf16;
    __syncthreads();
    int k1 = k0 + 32;
    if (k1 < K) {
      if (a32) pf32 = *(const float2*)((const float*)A + (size_t)(m0+row32)*K + k1 + kp32);
      else if (tid < 64) pf16 = *(const uint4*)((const u16*)A + (size_t)(m0+row16)*K + k1 + kp16);
    }
    bf16x8 af = *(const bf16x8*)&As[l16][quad*8];
    #pragma unroll
    for (int j = 0; j < JW; ++j) {
      int col = wave*(JW*16) + j*16 + l16;
      bf16x8 bfj = *(const bf16x8*)(BT + (size_t)col*K + k0 + quad*8);
      acc[j] = __builtin_amdgcn_mfma_f32_16x16x32_bf16(af, bfj, acc[j], 0, 0, 0);
    }
    __syncthreads();
  }
  #pragma unroll
  for (int j = 0; j < JW; ++j) {
    #pragma unroll
    for (int r = 0; r < 4; ++r) {
      int col = wave*(JW*16) + j*16 + l16;
      C[(size_t)(m0 + quad*4 + r)*ldc + col] = f2b(acc[j][r]);
    }
  }
}

// ---------- up GEMM: C[M][N] = A[M][*] * B, K=128, BT[N][128]; tiles 64x64 ----------
__global__ __launch_bounds__(256)
void k_gemm_up(const u16* A, int lda, int acol, const u16* BT, void* C, int ldc,
               const int* flag, int out_dyn) {
  __shared__ u16 As[64][40];
  int tid = threadIdx.x, wave = tid >> 6, lane = tid & 63, quad = lane >> 4, l16 = lane & 15;
  int n0 = blockIdx.x * 64, m0 = blockIdx.y * 64;
  bool o32 = out_dyn && flag[0];
  f32x4 acc[4] = {};
  int row = tid >> 2, kp = (tid & 3) * 8;
  #pragma unroll
  for (int k0 = 0; k0 < 128; k0 += 32) {
    *(uint4*)&As[row][kp] = *(const uint4*)(A + (size_t)(m0+row)*lda + acol + k0 + kp);
    __syncthreads();
    bf16x8 af = *(const bf16x8*)&As[wave*16 + l16][quad*8];
    #pragma unroll
    for (int j = 0; j < 4; ++j) {
      bf16x8 bfj = *(const bf16x8*)(BT + (size_t)(n0 + j*16 + l16)*128 + k0 + quad*8);
      acc[j] = __builtin_amdgcn_mfma_f32_16x16x32_bf16(af, bfj, acc[j], 0, 0, 0);
    }
    __syncthreads();
  }
  #pragma unroll
  for (int j = 0; j < 4; ++j) {
    #pragma unroll
    for (int r = 0; r < 4; ++r) {
      size_t ci = (size_t)(m0 + wave*16 + quad*4 + r)*ldc + n0 + j*16 + l16;
      float v = acc[j][r];
      if (o32) ((float*)C)[ci] = v; else ((u16*)C)[ci] = f2b(v);
    }
  }
}

// ---------- q post: RMSNorm + RoPE, IN-PLACE on [B*T][2048] ----------
__global__ __launch_bounds__(64)
void k_qpost(u16* qn, const u16* qw, const int* tok) {
  int bid = blockIdx.x;
  int h = bid & 15, bt = bid >> 4;
  int t = bt & 2047;
  int lane = threadIdx.x;
  size_t base = (size_t)bt * 2048 + h * 128;
  float x0 = b2f(qn[base + lane]);
  float x1 = b2f(qn[base + lane + 64]);
  float ss = wsum(x0*x0 + x1*x1);
  float inv = rsqrtf(ss * (1.0f/128.0f) + 1e-6f);
  float y0 = x0 * inv * b2f(qw[lane]);
  float y1 = x1 * inv * b2f(qw[lane + 64]);
  float pos = (float)(tok[0] + t);
  float invf = __expf(-(float)lane * (9.210340371976184f / 64.0f));
  float sn, cs; sincosf(pos * invf, &sn, &cs);
  qn[base + lane]      = f2b(y0*cs - y1*sn);
  qn[base + lane + 64] = f2b(y1*cs + y0*sn);
}

// ---------- k post: RMSNorm + RoPE, IN-PLACE on kvraw rows (cols 0..127) ----------
__global__ __launch_bounds__(64)
void k_kpost(u16* kv, const u16* kw, const int* spos) {
  int row = blockIdx.x;              // (b*1024+n)*16 + h
  int n = (row >> 4) & 1023;
  int lane = threadIdx.x;
  size_t base = (size_t)row * 256;
  float x0 = b2f(kv[base + lane]);
  float x1 = b2f(kv[base + lane + 64]);
  float ss = wsum(x0*x0 + x1*x1);
  float inv = rsqrtf(ss * (1.0f/128.0f) + 1e-6f);
  float y0 = x0 * inv * b2f(kw[lane]);
  float y1 = x1 * inv * b2f(kw[lane + 64]);
  float pos = (float)spos[n];
  float invf = __expf(-(float)lane * (9.210340371976184f / 64.0f));
  float sn, cs; sincosf(pos * invf, &sn, &cs);
  kv[base + lane]      = f2b(y0*cs - y1*sn);
  kv[base + lane + 64] = f2b(y1*cs + y0*sn);
}

// ---------- V transpose: kvraw v-cols (bf16) -> vtt[b,h,dh,n] (f16) ----------
__global__ __launch_bounds__(256)
void k_vtrans(const u16* kv, u16* vtt) {
  __shared__ u16 Vs[64][136];
  int t = threadIdx.x;
  int bid = blockIdx.x;              // (b*16+h)*16 + ng
  int ng = bid & 15, bh = bid >> 4;
  int b = bh >> 4, h = bh & 15;
  int n0 = ng * 64;
  int li = t >> 4, seg = (t & 15) * 8;
  #pragma unroll
  for (int p = 0; p < 4; ++p) {
    int i = li + p * 16;
    size_t row = (size_t)(b*1024 + n0 + i) * 16 + h;
    *(uint4*)&Vs[i][seg] = *(const uint4*)(kv + row*256 + 128 + seg);
  }
  __syncthreads();
  int dh = t >> 1, nh = (t & 1) * 32;
  u16 outv[32];
  #pragma unroll
  for (int i = 0; i < 32; ++i) outv[i] = f2h(b2f(Vs[nh + i][dh]));
  u16* dst = vtt + ((size_t)bh * 128 + dh) * 1024 + n0 + nh;
  *(uint4*)(dst)      = *(uint4*)&outv[0];
  *(uint4*)(dst + 8)  = *(uint4*)&outv[8];
  *(uint4*)(dst + 16) = *(uint4*)&outv[16];
  *(uint4*)(dst + 24) = *(uint4*)&outv[24];
}

// ---------- fused attention ----------
__global__ __launch_bounds__(256)
void k_attn(const u16* qn, const u16* kv, const u16* vtt, const u16* graw,
            const int* spos, const int* tok, const u16* sink, u16* o) {
  __shared__ u16 sc[16][1032];       // scores then weights (f16), padded
  __shared__ u16 Qt[16][128];
  __shared__ int pos_s[1024];
  __shared__ float rz_s[16];

  int tid = threadIdx.x;
  int wave = tid >> 6, lane = tid & 63, quad = lane >> 4, l16 = lane & 15;
  int bid = blockIdx.x;
  int tile = bid & 127, bh = bid >> 7;
  int h = bh & 15, b = bh >> 4;
  int t0 = tile * 16;

  {
    int i = tid >> 4, seg = (tid & 15) * 8;
    *(uint4*)&Qt[i][seg] = *(const uint4*)(qn + (size_t)(b*2048 + t0 + i)*2048 + h*128 + seg);
    ((int4*)pos_s)[tid] = ((const int4*)spos)[tid];
  }
  __syncthreads();

  bf16x8 af[4];
  #pragma unroll
  for (int ks = 0; ks < 4; ++ks) af[ks] = *(const bf16x8*)&Qt[l16][ks*32 + quad*8];
  int tok0 = tok[0];
  const u16* kvb = kv + (size_t)b * 4194304 + h * 256;

  // phase 1: scores -> sc (f16)
  #pragma unroll 2
  for (int p = 0; p < 16; ++p) {
    int n0 = p*64 + wave*16;
    f32x4 c = {};
    const u16* krow = kvb + (size_t)(n0 + l16) * 4096;
    #pragma unroll
    for (int ks = 0; ks < 4; ++ks) {
      bf16x8 bfr = *(const bf16x8*)(krow + ks*32 + quad*8);
      c = __builtin_amdgcn_mfma_f32_16x16x32_bf16(af[ks], bfr, c, 0, 0, 0);
    }
    int n = n0 + l16;
    int pn = pos_s[n];
    #pragma unroll
    for (int r = 0; r < 4; ++r) {
      int t = quad*4 + r;
      float s = c[r] * 0.08838834764831845f;
      if (pn >= tok0 + t0 + t) s = -INFINITY;
      sc[t][n] = f2h(s);
    }
  }
  __syncthreads();

  float sinkv = b2f(sink[h]);

  // phase 2: per-t top-64 threshold + softmax weights (no barriers, wave-private rows)
  #pragma unroll 1
  for (int s5 = 0; s5 < 4; ++s5) {
    int tl = wave*4 + s5;
    uint4 r0 = *(const uint4*)&sc[tl][lane*16];
    uint4 r1 = *(const uint4*)&sc[tl][lane*16 + 8];
    float sv[16]; int key[16];
    float mx = -INFINITY;
    #pragma unroll
    for (int j = 0; j < 16; ++j) {
      u16 hb = (j < 8) ? ((const u16*)&r0)[j] : ((const u16*)&r1)[j-8];
      float f = h2f(hb);
      sv[j] = f; mx = fmaxf(mx, f);
      float fs = fminf(fmaxf(f * 256.0f + 2048.0f, 0.0f), 4095.0f);
      key[j] = (int)fs;
    }
    mx = wmax(mx);
    int lo = 0, hi = 4096;
    #pragma unroll 1
    for (int it = 0; it < 12; ++it) {
      int mid = (lo + hi) >> 1;
      int c = 0;
      #pragma unroll
      for (int j = 0; j < 16; ++j) c += (key[j] >= mid);
      c = wsumi(c);
      if (c >= 64) lo = mid; else hi = mid;
    }
    float m = fmaxf(mx, sinkv);
    float zp = 0.f;
    u16 wq[16];
    #pragma unroll
    for (int j = 0; j < 16; ++j) {
      float e = (key[j] >= lo && sv[j] > -1e37f) ? __expf(sv[j] - m) : 0.f;
      zp += e;
      wq[j] = f2h(e);
    }
    float Z = wsum(zp) + __expf(sinkv - m);
    if (lane == 0) rz_s[tl] = 1.0f / Z;
    *(uint4*)&sc[tl][lane*16]     = *(uint4*)&wq[0];
    *(uint4*)&sc[tl][lane*16 + 8] = *(uint4*)&wq[8];
  }
  __syncthreads();

  // phase 3: dense PV via MFMA f16; wave handles dh cols [wave*32, wave*32+32)
  const u16* vbase = vtt + (size_t)bh * 131072;
  int dh0 = wave * 32;
  f32x4 acc0 = {}, acc1 = {};
  #pragma unroll 2
  for (int kk = 0; kk < 32; ++kk) {
    f16x8 a  = *(const f16x8*)&sc[l16][kk*32 + quad*8];
    f16x8 b0 = *(const f16x8*)(vbase + (size_t)(dh0 + l16)*1024 + kk*32 + quad*8);
    f16x8 b1 = *(const f16x8*)(vbase + (size_t)(dh0 + 16 + l16)*1024 + kk*32 + quad*8);
    acc0 = __builtin_amdgcn_mfma_f32_16x16x32_f16(a, b0, acc0, 0, 0, 0);
    acc1 = __builtin_amdgcn_mfma_f32_16x16x32_f16(a, b1, acc1, 0, 0, 0);
  }

  // epilogue: *1/Z, *sigmoid(gate), store
  #pragma unroll
  for (int r = 0; r < 4; ++r) {
    int t = quad*4 + r;
    float rz = rz_s[t];
    size_t oi = ((size_t)(b*2048 + t0 + t))*2048 + h*128 + dh0 + l16;
    float g0 = 1.0f / (1.0f + __expf(-b2f(graw[oi])));
    o[oi] = f2b(acc0[r] * rz * g0);
    float g1 = 1.0f / (1.0f + __expf(-b2f(graw[oi + 16])));
    o[oi + 16] = f2b(acc1[r] * rz * g1);
  }
}

extern "C" void kernel_launch(void* const* d_in, const int* in_sizes, int n_in,
                              void* d_out, int out_size, void* d_ws, size_t ws_size,
                              hipStream_t stream) {
  char* ws = (char*)d_ws;
  int* flag = (int*)(ws + 0);
  u16* wb = (u16*)(ws + 4096);

  // wb element offsets
  u16* BdT  = wb + 0;        // [256][2048]
  u16* BkvT = wb + 524288;   // [256][512]
  u16* WquT = wb + 655360;   // [2048][128]
  u16* WguT = wb + 917504;   // [2048][128]
  u16* WodT = wb + 1179648;  // [128][2048]
  u16* WouT = wb + 1441792;  // [2048][128]
  u16* cqw  = wb + 1703936;
  u16* ckw  = wb + 1704064;
  u16* csink= wb + 1704192;

  // byte offsets
  const size_t O_QGLAT = 4198400;   // [4096][256] bf16, 2MB (olat aliases later)
  const size_t O_QRAW  = 6295552;   // [4096][2048] bf16, 16MB (q normed in-place)
  const size_t O_GRAW  = 23072768;  // [4096][2048] bf16, 16MB
  const size_t O_KV    = 39849984;  // [32768][256] bf16, 16MB (k normed in-place)
  const size_t O_VTT   = 56627200;  // [32][128][1024] f16, 8MB
  const size_t O_O     = 65015808;  // [4096][2048] bf16, 16MB

  const int* spos = (const int*)d_in[2];
  const int* tok  = (const int*)d_in[3];

  k_detect<<<1, 64, 0, stream>>>((const u32*)d_in[0], flag);

  // weight transposes
  k_wtrans<<<dim3(2,32), 256, 0, stream>>>(d_in[4],  BdT,              2048, 128,  flag); // Wq_down
  k_wtrans<<<dim3(2,32), 256, 0, stream>>>(d_in[6],  BdT + 128*2048,   2048, 128,  flag); // Wg_down
  k_wtrans<<<dim3(2,8),  256, 0, stream>>>(d_in[10], BkvT,             512,  128,  flag); // Wk_up
  k_wtrans<<<dim3(2,8),  256, 0, stream>>>(d_in[11], BkvT + 128*512,   512,  128,  flag); // Wv_up
  k_wtrans<<<dim3(32,2), 256, 0, stream>>>(d_in[5],  WquT,             128,  2048, flag); // Wq_up
  k_wtrans<<<dim3(32,2), 256, 0, stream>>>(d_in[7],  WguT,             128,  2048, flag); // Wg_up
  k_wtrans<<<dim3(2,32), 256, 0, stream>>>(d_in[8],  WodT,             2048, 128,  flag); // Wo_down
  k_wtrans<<<dim3(32,2), 256, 0, stream>>>(d_in[9],  WouT,             128,  2048, flag); // Wo_up
  k_vecconv<<<1, 256, 0, stream>>>(d_in[12], d_in[13], d_in[14], cqw, ckw, csink, flag);

  // fused down projections (read x / snapshots once)
  k_gemm_skinny<4,1><<<256,  256, 0, stream>>>(d_in[0], BdT,  (u16*)(ws + O_QGLAT), 2048, 256, flag);
  k_gemm_skinny<4,1><<<2048, 256, 0, stream>>>(d_in[1], BkvT, (u16*)(ws + O_KV),    512,  256, flag);

  // up projections
  k_gemm_up<<<dim3(32,64), 256, 0, stream>>>((const u16*)(ws + O_QGLAT), 256, 0,   WquT, ws + O_QRAW, 2048, flag, 0);
  k_gemm_up<<<dim3(32,64), 256, 0, stream>>>((const u16*)(ws + O_QGLAT), 256, 128, WguT, ws + O_GRAW, 2048, flag, 0);

  // norm + rope (in place) and V transpose
  k_qpost<<<65536, 64, 0, stream>>>((u16*)(ws + O_QRAW), cqw, tok);
  k_kpost<<<32768, 64, 0, stream>>>((u16*)(ws + O_KV), ckw, spos);
  k_vtrans<<<512, 256, 0, stream>>>((const u16*)(ws + O_KV), (u16*)(ws + O_VTT));

  // attention
  k_attn<<<4096, 256, 0, stream>>>((const u16*)(ws + O_QRAW), (const u16*)(ws + O_KV),
                                   (const u16*)(ws + O_VTT), (const u16*)(ws + O_GRAW),
                                   spos, tok, csink, (u16*)(ws + O_O));

  // output projections (olat aliases dead qglat region)
  k_gemm_skinny<2,0><<<256, 256, 0, stream>>>(ws + O_O, WodT, (u16*)(ws + O_QGLAT), 2048, 128, flag);
  k_gemm_up<<<dim3(32,64), 256, 0, stream>>>((const u16*)(ws + O_QGLAT), 128, 0, WouT, d_out, 2048, flag, 1);
}

// Round 3
// 716.692 us; speedup vs baseline: 1.3781x; 1.1474x over previous
//
#include <hip/hip_runtime.h>

typedef unsigned short u16;
typedef unsigned int u32;
typedef __attribute__((ext_vector_type(8))) short bf16x8;
typedef __attribute__((ext_vector_type(8))) _Float16 f16x8;
typedef __attribute__((ext_vector_type(4))) float f32x4;

__device__ __forceinline__ float b2f(u16 u) {
  union { u32 i; float f; } v; v.i = ((u32)u) << 16; return v.f;
}
__device__ __forceinline__ u16 f2b(float f) {
  u32 u = __builtin_bit_cast(u32, f);
  u32 r = u + 0x7FFFu + ((u >> 16) & 1u);
  return (u16)(r >> 16);
}
__device__ __forceinline__ u16 f2h(float f) {
  return __builtin_bit_cast(u16, (_Float16)f);
}
__device__ __forceinline__ float h2f(u16 u) {
  return (float)__builtin_bit_cast(_Float16, u);
}
__device__ __forceinline__ float wsum(float v) {
  #pragma unroll
  for (int o = 32; o; o >>= 1) v += __shfl_xor(v, o);
  return v;
}
__device__ __forceinline__ int wsumi(int v) {
  #pragma unroll
  for (int o = 32; o; o >>= 1) v += __shfl_xor(v, o);
  return v;
}
__device__ __forceinline__ float wmax(float v) {
  #pragma unroll
  for (int o = 32; o; o >>= 1) v = fmaxf(v, __shfl_xor(v, o));
  return v;
}

// ---------- dtype detector: flag=0 bf16 storage, flag=1 fp32 ----------
__global__ void k_detect(const u32* x, int* flag) {
  int lane = threadIdx.x;
  u32 w = x[lane * 131 + 7];
  float v = b2f((u16)(w & 0xFFFF));
  float a = fabsf(v);
  bool sane = (a > 1e-3f) && (a < 100.0f);
  unsigned long long m = __ballot(sane);
  if (lane == 0) flag[0] = (__popcll(m) >= 32) ? 0 : 1;
}

// ---------- weight transpose+convert: W[K][N] (f32/bf16) -> BT[col][K] bf16 ----------
__global__ __launch_bounds__(256)
void k_wtrans(const void* src, u16* dst, int K, int N, const int* flag) {
  __shared__ u16 Ts[64][66];
  int t = threadIdx.x;
  int col0 = blockIdx.x * 64, k0 = blockIdx.y * 64;
  int dt = flag[0];
  int lr = t >> 4, lc = (t & 15) * 4;
  if (dt) {
    #pragma unroll
    for (int p = 0; p < 4; ++p) {
      int kr = lr + p * 16;
      float4 v = *(const float4*)((const float*)src + (size_t)(k0 + kr) * N + col0 + lc);
      Ts[kr][lc+0] = f2b(v.x); Ts[kr][lc+1] = f2b(v.y);
      Ts[kr][lc+2] = f2b(v.z); Ts[kr][lc+3] = f2b(v.w);
    }
  } else {
    #pragma unroll
    for (int p = 0; p < 4; ++p) {
      int kr = lr + p * 16;
      uint2 v = *(const uint2*)((const u16*)src + (size_t)(k0 + kr) * N + col0 + lc);
      *(uint2*)&Ts[kr][lc] = v;
    }
  }
  __syncthreads();
  int col = t >> 2, ks = (t & 3) * 16;
  u16 tmp[16];
  #pragma unroll
  for (int i = 0; i < 16; ++i) tmp[i] = Ts[ks + i][col];
  u16* dp = dst + (size_t)(col0 + col) * K + k0 + ks;
  *(uint4*)dp = *(uint4*)&tmp[0];
  *(uint4*)(dp + 8) = *(uint4*)&tmp[8];
}

// ---------- small vector convert ----------
__global__ void k_vecconv(const void* qw, const void* kw, const void* sk,
                          u16* dq, u16* dk, u16* dsnk, const int* flag) {
  int t = threadIdx.x; int dt = flag[0];
  if (t < 128) dq[t] = dt ? f2b(((const float*)qw)[t]) : ((const u16*)qw)[t];
  else if (t < 256) dk[t-128] = dt ? f2b(((const float*)kw)[t-128]) : ((const u16*)kw)[t-128];
  if (t < 16) dsnk[t] = dt ? f2b(((const float*)sk)[t]) : ((const u16*)sk)[t];
}

// ---------- skinny GEMM: C = A[M][K] * B, BT[N][K] given; tile M=16, N=JW*64 ----------
// Output split: cols [0,128) -> C0, cols [128,256) -> C1 (both ld=128).
template<int JW, int ADYN>
__global__ __launch_bounds__(256)
void k_gemm_skinny(const void* A, const u16* BT, u16* C0, u16* C1, int K, const int* flag) {
  __shared__ u16 As[16][40];
  int tid = threadIdx.x, wave = tid >> 6, lane = tid & 63, quad = lane >> 4, l16 = lane & 15;
  int m0 = blockIdx.x * 16;
  bool a32 = ADYN && flag[0];
  f32x4 acc[JW];
  #pragma unroll
  for (int j = 0; j < JW; ++j) acc[j] = (f32x4){0.f,0.f,0.f,0.f};

  int row32 = tid >> 4, kp32 = (tid & 15) * 2;
  int row16 = tid >> 2, kp16 = (tid & 3) * 8;
  float2 pf32 = {};
  uint4 pf16 = {};
  if (a32) pf32 = *(const float2*)((const float*)A + (size_t)(m0+row32)*K + kp32);
  else if (tid < 64) pf16 = *(const uint4*)((const u16*)A + (size_t)(m0+row16)*K + kp16);

  for (int k0 = 0; k0 < K; k0 += 32) {
    if (a32) { As[row32][kp32] = f2b(pf32.x); As[row32][kp32+1] = f2b(pf32.y); }
    else if (tid < 64) *(uint4*)&As[row16][kp16] = pf16;
    __syncthreads();
    int k1 = k0 + 32;
    if (k1 < K) {
      if (a32) pf32 = *(const float2*)((const float*)A + (size_t)(m0+row32)*K + k1 + kp32);
      else if (tid < 64) pf16 = *(const uint4*)((const u16*)A + (size_t)(m0+row16)*K + k1 + kp16);
    }
    bf16x8 af = *(const bf16x8*)&As[l16][quad*8];
    #pragma unroll
    for (int j = 0; j < JW; ++j) {
      int col = wave*(JW*16) + j*16 + l16;
      bf16x8 bfj = *(const bf16x8*)(BT + (size_t)col*K + k0 + quad*8);
      acc[j] = __builtin_amdgcn_mfma_f32_16x16x32_bf16(af, bfj, acc[j], 0, 0, 0);
    }
    __syncthreads();
  }
  #pragma unroll
  for (int j = 0; j < JW; ++j) {
    int col = wave*(JW*16) + j*16 + l16;
    u16* Cp = (col < 128) ? C0 : C1;
    int cc = col & 127;
    #pragma unroll
    for (int r = 0; r < 4; ++r)
      Cp[(size_t)(m0 + quad*4 + r)*128 + cc] = f2b(acc[j][r]);
  }
}

// ---------- up GEMM: C[M][N] = A[M][128] * B, BT[N][128]; tiles 64x64 ----------
__global__ __launch_bounds__(256)
void k_gemm_up(const u16* A, const u16* BT, void* C, int ldc,
               const int* flag, int out_dyn) {
  __shared__ u16 As[64][40];
  int tid = threadIdx.x, wave = tid >> 6, lane = tid & 63, quad = lane >> 4, l16 = lane & 15;
  int n0 = blockIdx.x * 64, m0 = blockIdx.y * 64;
  bool o32 = out_dyn && flag[0];
  f32x4 acc[4] = {};
  int row = tid >> 2, kp = (tid & 3) * 8;
  #pragma unroll
  for (int k0 = 0; k0 < 128; k0 += 32) {
    *(uint4*)&As[row][kp] = *(const uint4*)(A + (size_t)(m0+row)*128 + k0 + kp);
    __syncthreads();
    bf16x8 af = *(const bf16x8*)&As[wave*16 + l16][quad*8];
    #pragma unroll
    for (int j = 0; j < 4; ++j) {
      bf16x8 bfj = *(const bf16x8*)(BT + (size_t)(n0 + j*16 + l16)*128 + k0 + quad*8);
      acc[j] = __builtin_amdgcn_mfma_f32_16x16x32_bf16(af, bfj, acc[j], 0, 0, 0);
    }
    __syncthreads();
  }
  #pragma unroll
  for (int j = 0; j < 4; ++j) {
    #pragma unroll
    for (int r = 0; r < 4; ++r) {
      size_t ci = (size_t)(m0 + wave*16 + quad*4 + r)*ldc + n0 + j*16 + l16;
      float v = acc[j][r];
      if (o32) ((float*)C)[ci] = v; else ((u16*)C)[ci] = f2b(v);
    }
  }
}

// ---------- q post: RMSNorm + RoPE, IN-PLACE on [B*T][2048]; 4 waves/block ----------
__global__ __launch_bounds__(256)
void k_qpost(u16* qn, const u16* qw, const int* tok) {
  int wave = threadIdx.x >> 6, lane = threadIdx.x & 63;
  int rr = blockIdx.x * 4 + wave;        // bt*16 + h
  int h = rr & 15, bt = rr >> 4;
  int t = bt & 2047;
  size_t base = (size_t)bt * 2048 + h * 128;
  float x0 = b2f(qn[base + lane]);
  float x1 = b2f(qn[base + lane + 64]);
  float ss = wsum(x0*x0 + x1*x1);
  float inv = rsqrtf(ss * (1.0f/128.0f) + 1e-6f);
  float y0 = x0 * inv * b2f(qw[lane]);
  float y1 = x1 * inv * b2f(qw[lane + 64]);
  float pos = (float)(tok[0] + t);
  float invf = __expf(-(float)lane * (9.210340371976184f / 64.0f));
  float sn, cs; sincosf(pos * invf, &sn, &cs);
  qn[base + lane]      = f2b(y0*cs - y1*sn);
  qn[base + lane + 64] = f2b(y1*cs + y0*sn);
}

// ---------- k post: RMSNorm + RoPE; kraw[(b*N+n)*16+h][128] -> kT[(b*16+h)*1024+n][128] ----------
__global__ __launch_bounds__(256)
void k_kpost(const u16* kraw, u16* kT, const u16* kw, const int* spos) {
  int wave = threadIdx.x >> 6, lane = threadIdx.x & 63;
  int rr = blockIdx.x * 4 + wave;        // (b*1024+n)*16 + h
  int n = (rr >> 4) & 1023, b = rr >> 14, h = rr & 15;
  size_t base = (size_t)rr * 128;
  float x0 = b2f(kraw[base + lane]);
  float x1 = b2f(kraw[base + lane + 64]);
  float ss = wsum(x0*x0 + x1*x1);
  float inv = rsqrtf(ss * (1.0f/128.0f) + 1e-6f);
  float y0 = x0 * inv * b2f(kw[lane]);
  float y1 = x1 * inv * b2f(kw[lane + 64]);
  float pos = (float)spos[n];
  float invf = __expf(-(float)lane * (9.210340371976184f / 64.0f));
  float sn, cs; sincosf(pos * invf, &sn, &cs);
  size_t ob = ((size_t)(b*16 + h) * 1024 + n) * 128;
  kT[ob + lane]      = f2b(y0*cs - y1*sn);
  kT[ob + lane + 64] = f2b(y1*cs + y0*sn);
}

// ---------- V transpose: vraw[(b*N+n)*16+h][128] (bf16) -> vtt[b,h,dh,n] (f16) ----------
__global__ __launch_bounds__(256)
void k_vtrans(const u16* vraw, u16* vtt) {
  __shared__ u16 Vs[64][136];
  int t = threadIdx.x;
  int bid = blockIdx.x;              // (b*16+h)*16 + ng
  int ng = bid & 15, bh = bid >> 4;
  int b = bh >> 4, h = bh & 15;
  int n0 = ng * 64;
  int li = t >> 4, seg = (t & 15) * 8;
  #pragma unroll
  for (int p = 0; p < 4; ++p) {
    int i = li + p * 16;
    size_t row = (size_t)(b*1024 + n0 + i) * 16 + h;
    *(uint4*)&Vs[i][seg] = *(const uint4*)(vraw + row*128 + seg);
  }
  __syncthreads();
  int dh = t >> 1, nh = (t & 1) * 32;
  u16 outv[32];
  #pragma unroll
  for (int i = 0; i < 32; ++i) outv[i] = f2h(b2f(Vs[nh + i][dh]));
  u16* dst = vtt + ((size_t)bh * 128 + dh) * 1024 + n0 + nh;
  *(uint4*)(dst)      = *(uint4*)&outv[0];
  *(uint4*)(dst + 8)  = *(uint4*)&outv[8];
  *(uint4*)(dst + 16) = *(uint4*)&outv[16];
  *(uint4*)(dst + 24) = *(uint4*)&outv[24];
}

// ---------- fused attention ----------
__global__ __launch_bounds__(256, 4)
void k_attn(const u16* qn, const u16* kT, const u16* vtt, const u16* graw,
            const int* spos, const int* tok, const u16* sink, u16* o) {
  __shared__ u16 sc[16][1032];       // scores then weights (f16), padded
  __shared__ int pos_s[1024];
  __shared__ float rz_s[16];

  int tid = threadIdx.x;
  int wave = tid >> 6, lane = tid & 63, quad = lane >> 4, l16 = lane & 15;
  int bid = blockIdx.x;
  int tile = bid & 127, bh = bid >> 7;
  int h = bh & 15, b = bh >> 4;
  int t0 = tile * 16;

  ((int4*)pos_s)[tid] = ((const int4*)spos)[tid];

  // Q fragments straight from global (same values as the old LDS round-trip)
  bf16x8 af[4];
  {
    const u16* qrow = qn + (size_t)(b*2048 + t0 + l16)*2048 + h*128 + quad*8;
    #pragma unroll
    for (int ks = 0; ks < 4; ++ks) {
      uint4 qv = *(const uint4*)(qrow + ks*32);
      af[ks] = __builtin_bit_cast(bf16x8, qv);
    }
  }
  int tok0 = tok[0];
  __syncthreads();

  // phase 1: scores -> sc (f16), K from contiguous kT with register prefetch
  const u16* kTb = kT + (size_t)bh * 131072;   // 1024*128
  int nrow = wave*16 + l16;
  uint4 kf[4];
  {
    const u16* kr = kTb + (size_t)nrow * 128 + quad*8;
    #pragma unroll
    for (int ks = 0; ks < 4; ++ks) kf[ks] = *(const uint4*)(kr + ks*32);
  }
  #pragma unroll 1
  for (int p = 0; p < 16; ++p) {
    uint4 kn[4];
    if (p < 15) {
      const u16* kr = kTb + (size_t)((p+1)*64 + nrow) * 128 + quad*8;
      #pragma unroll
      for (int ks = 0; ks < 4; ++ks) kn[ks] = *(const uint4*)(kr + ks*32);
    }
    f32x4 c = {};
    #pragma unroll
    for (int ks = 0; ks < 4; ++ks)
      c = __builtin_amdgcn_mfma_f32_16x16x32_bf16(af[ks], __builtin_bit_cast(bf16x8, kf[ks]), c, 0, 0, 0);
    int n = p*64 + nrow;
    int pn = pos_s[n];
    #pragma unroll
    for (int r = 0; r < 4; ++r) {
      int t = quad*4 + r;
      float s = c[r] * 0.08838834764831845f;
      if (pn >= tok0 + t0 + t) s = -INFINITY;
      sc[t][n] = f2h(s);
    }
    #pragma unroll
    for (int ks = 0; ks < 4; ++ks) kf[ks] = kn[ks];
  }
  __syncthreads();

  float sinkv = b2f(sink[h]);

  // phase 2: per-t top-64 threshold + softmax weights (wave-private rows)
  #pragma unroll 1
  for (int s5 = 0; s5 < 4; ++s5) {
    int tl = wave*4 + s5;
    uint4 r0 = *(const uint4*)&sc[tl][lane*16];
    uint4 r1 = *(const uint4*)&sc[tl][lane*16 + 8];
    float sv[16]; int key[16];
    float mx = -INFINITY;
    #pragma unroll
    for (int j = 0; j < 16; ++j) {
      u16 hb = (j < 8) ? ((const u16*)&r0)[j] : ((const u16*)&r1)[j-8];
      float f = h2f(hb);
      sv[j] = f; mx = fmaxf(mx, f);
      float fs = fminf(fmaxf(f * 256.0f + 2048.0f, 0.0f), 4095.0f);
      key[j] = (int)fs;
    }
    mx = wmax(mx);
    int lo = 0, hi = 4096;
    #pragma unroll 1
    for (int it = 0; it < 12; ++it) {
      int mid = (lo + hi) >> 1;
      int c = 0;
      #pragma unroll
      for (int j = 0; j < 16; ++j) c += (key[j] >= mid);
      c = wsumi(c);
      if (c >= 64) lo = mid; else hi = mid;
    }
    float m = fmaxf(mx, sinkv);
    float zp = 0.f;
    u16 wq[16];
    #pragma unroll
    for (int j = 0; j < 16; ++j) {
      float e = (key[j] >= lo && sv[j] > -1e37f) ? __expf(sv[j] - m) : 0.f;
      zp += e;
      wq[j] = f2h(e);
    }
    float Z = wsum(zp) + __expf(sinkv - m);
    if (lane == 0) rz_s[tl] = 1.0f / Z;
    *(uint4*)&sc[tl][lane*16]     = *(uint4*)&wq[0];
    *(uint4*)&sc[tl][lane*16 + 8] = *(uint4*)&wq[8];
  }
  __syncthreads();

  // phase 3: dense PV via MFMA f16 with register prefetch of V fragments
  const u16* vbase = vtt + (size_t)bh * 131072;
  int dh0 = wave * 32;
  const u16* vr0 = vbase + (size_t)(dh0 + l16)*1024 + quad*8;
  const u16* vr1 = vbase + (size_t)(dh0 + 16 + l16)*1024 + quad*8;
  f32x4 acc0 = {}, acc1 = {};
  uint4 vf0 = *(const uint4*)vr0;
  uint4 vf1 = *(const uint4*)vr1;
  #pragma unroll 1
  for (int kk = 0; kk < 32; ++kk) {
    uint4 vn0, vn1;
    if (kk < 31) {
      vn0 = *(const uint4*)(vr0 + (kk+1)*32);
      vn1 = *(const uint4*)(vr1 + (kk+1)*32);
    }
    f16x8 a = *(const f16x8*)&sc[l16][kk*32 + quad*8];
    acc0 = __builtin_amdgcn_mfma_f32_16x16x32_f16(a, __builtin_bit_cast(f16x8, vf0), acc0, 0, 0, 0);
    acc1 = __builtin_amdgcn_mfma_f32_16x16x32_f16(a, __builtin_bit_cast(f16x8, vf1), acc1, 0, 0, 0);
    vf0 = vn0; vf1 = vn1;
  }

  // epilogue: *1/Z, *sigmoid(gate), store (o may alias graw; same-thread RaW only)
  #pragma unroll
  for (int r = 0; r < 4; ++r) {
    int t = quad*4 + r;
    float rz = rz_s[t];
    size_t oi = ((size_t)(b*2048 + t0 + t))*2048 + h*128 + dh0 + l16;
    float g0 = 1.0f / (1.0f + __expf(-b2f(graw[oi])));
    float g1 = 1.0f / (1.0f + __expf(-b2f(graw[oi + 16])));
    o[oi] = f2b(acc0[r] * rz * g0);
    o[oi + 16] = f2b(acc1[r] * rz * g1);
  }
}

extern "C" void kernel_launch(void* const* d_in, const int* in_sizes, int n_in,
                              void* d_out, int out_size, void* d_ws, size_t ws_size,
                              hipStream_t stream) {
  char* ws = (char*)d_ws;
  int* flag = (int*)(ws + 0);
  u16* wb = (u16*)(ws + 4096);

  // wb element offsets
  u16* BdT  = wb + 0;        // [256][2048]
  u16* BkvT = wb + 524288;   // [256][512]
  u16* WquT = wb + 655360;   // [2048][128]
  u16* WguT = wb + 917504;   // [2048][128]
  u16* WodT = wb + 1179648;  // [128][2048]
  u16* WouT = wb + 1441792;  // [2048][128]
  u16* cqw  = wb + 1703936;
  u16* ckw  = wb + 1704064;
  u16* csink= wb + 1704192;

  // byte offsets
  const size_t O_QLAT = 4198400;    // [4096][128] bf16, 1MB (olat aliases later)
  const size_t O_GLAT = 5246976;    // [4096][128] bf16, 1MB
  const size_t O_QRAW = 6295552;    // [4096][2048] bf16, 16MB (q normed in-place)
  const size_t O_GRAW = 23072768;   // [4096][2048] bf16, 16MB (attn writes out in-place)
  const size_t O_KRAW = 39849984;   // [32768][128] bf16, 8MB
  const size_t O_VRAW = 48238592;   // [32768][128] bf16, 8MB
  const size_t O_KT   = 56627200;   // [32][1024][128] bf16, 8MB
  const size_t O_VTT  = 65015808;   // [32][128][1024] f16, 8MB

  const int* spos = (const int*)d_in[2];
  const int* tok  = (const int*)d_in[3];

  k_detect<<<1, 64, 0, stream>>>((const u32*)d_in[0], flag);

  // weight transposes
  k_wtrans<<<dim3(2,32), 256, 0, stream>>>(d_in[4],  BdT,              2048, 128,  flag); // Wq_down
  k_wtrans<<<dim3(2,32), 256, 0, stream>>>(d_in[6],  BdT + 128*2048,   2048, 128,  flag); // Wg_down
  k_wtrans<<<dim3(2,8),  256, 0, stream>>>(d_in[10], BkvT,             512,  128,  flag); // Wk_up
  k_wtrans<<<dim3(2,8),  256, 0, stream>>>(d_in[11], BkvT + 128*512,   512,  128,  flag); // Wv_up
  k_wtrans<<<dim3(32,2), 256, 0, stream>>>(d_in[5],  WquT,             128,  2048, flag); // Wq_up
  k_wtrans<<<dim3(32,2), 256, 0, stream>>>(d_in[7],  WguT,             128,  2048, flag); // Wg_up
  k_wtrans<<<dim3(2,32), 256, 0, stream>>>(d_in[8],  WodT,             2048, 128,  flag); // Wo_down
  k_wtrans<<<dim3(32,2), 256, 0, stream>>>(d_in[9],  WouT,             128,  2048, flag); // Wo_up
  k_vecconv<<<1, 256, 0, stream>>>(d_in[12], d_in[13], d_in[14], cqw, ckw, csink, flag);

  // fused down projections (read x / snapshots once), split outputs
  k_gemm_skinny<4,1><<<256,  256, 0, stream>>>(d_in[0], BdT,
      (u16*)(ws + O_QLAT), (u16*)(ws + O_GLAT), 2048, flag);
  k_gemm_skinny<4,1><<<2048, 256, 0, stream>>>(d_in[1], BkvT,
      (u16*)(ws + O_KRAW), (u16*)(ws + O_VRAW), 512, flag);

  // up projections
  k_gemm_up<<<dim3(32,64), 256, 0, stream>>>((const u16*)(ws + O_QLAT), WquT, ws + O_QRAW, 2048, flag, 0);
  k_gemm_up<<<dim3(32,64), 256, 0, stream>>>((const u16*)(ws + O_GLAT), WguT, ws + O_GRAW, 2048, flag, 0);

  // norm + rope and transposes
  k_qpost<<<16384, 256, 0, stream>>>((u16*)(ws + O_QRAW), cqw, tok);
  k_kpost<<<8192, 256, 0, stream>>>((const u16*)(ws + O_KRAW), (u16*)(ws + O_KT), ckw, spos);
  k_vtrans<<<512, 256, 0, stream>>>((const u16*)(ws + O_VRAW), (u16*)(ws + O_VTT));

  // attention (output in-place over GRAW)
  k_attn<<<4096, 256, 0, stream>>>((const u16*)(ws + O_QRAW), (const u16*)(ws + O_KT),
                                   (const u16*)(ws + O_VTT), (const u16*)(ws + O_GRAW),
                                   spos, tok, csink, (u16*)(ws + O_GRAW));

  // output projections (olat into dead QLAT region)
  k_gemm_skinny<2,0><<<256, 256, 0, stream>>>(ws + O_GRAW, WodT,
      (u16*)(ws + O_QLAT), (u16*)(ws + O_QLAT), 2048, flag);
  k_gemm_up<<<dim3(32,64), 256, 0, stream>>>((const u16*)(ws + O_QLAT), WouT, d_out, 2048, flag, 1);
}

// Round 4
// 531.293 us; speedup vs baseline: 1.8590x; 1.3490x over previous
//
#include <hip/hip_runtime.h>

typedef unsigned short u16;
typedef unsigned int u32;
typedef __attribute__((ext_vector_type(8))) short bf16x8;
typedef __attribute__((ext_vector_type(8))) _Float16 f16x8;
typedef __attribute__((ext_vector_type(4))) float f32x4;

__device__ __forceinline__ float b2f(u16 u) {
  union { u32 i; float f; } v; v.i = ((u32)u) << 16; return v.f;
}
__device__ __forceinline__ u16 f2b(float f) {
  u32 u = __builtin_bit_cast(u32, f);
  u32 r = u + 0x7FFFu + ((u >> 16) & 1u);
  return (u16)(r >> 16);
}
__device__ __forceinline__ u16 f2h(float f) {
  return __builtin_bit_cast(u16, (_Float16)f);
}
__device__ __forceinline__ float h2f(u16 u) {
  return (float)__builtin_bit_cast(_Float16, u);
}
__device__ __forceinline__ float wsum(float v) {
  #pragma unroll
  for (int o = 32; o; o >>= 1) v += __shfl_xor(v, o);
  return v;
}
__device__ __forceinline__ float wmax(float v) {
  #pragma unroll
  for (int o = 32; o; o >>= 1) v = fmaxf(v, __shfl_xor(v, o));
  return v;
}

// ---------- dtype detector: flag=0 bf16 storage, flag=1 fp32 ----------
__global__ void k_detect(const u32* x, int* flag) {
  int lane = threadIdx.x;
  u32 w = x[lane * 131 + 7];
  float v = b2f((u16)(w & 0xFFFF));
  float a = fabsf(v);
  bool sane = (a > 1e-3f) && (a < 100.0f);
  unsigned long long m = __ballot(sane);
  if (lane == 0) flag[0] = (__popcll(m) >= 32) ? 0 : 1;
}

// ---------- all weight transposes + vec convert in ONE launch ----------
struct WtArgs {
  const void* s[8];
  const void* vq; const void* vk; const void* vs;
};
__global__ __launch_bounds__(256)
void k_wtrans_all(WtArgs a, u16* wb, const int* flag) {
  __shared__ u16 Ts[64][66];
  int id = blockIdx.x, t = threadIdx.x, dt = flag[0];
  if (id == 416) {  // vec convert
    u16* dq = wb + 1703936; u16* dk = wb + 1704064; u16* ds = wb + 1704192;
    if (t < 128) dq[t] = dt ? f2b(((const float*)a.vq)[t]) : ((const u16*)a.vq)[t];
    else if (t < 256) dk[t-128] = dt ? f2b(((const float*)a.vk)[t-128]) : ((const u16*)a.vk)[t-128];
    if (t < 16) ds[t] = dt ? f2b(((const float*)a.vs)[t]) : ((const u16*)a.vs)[t];
    return;
  }
  const int cum[9] = {0,64,128,144,160,224,288,352,416};
  const int gsh[8] = {1,1,1,1,5,5,1,5};
  const int Ks[8]  = {2048,2048,512,512,128,128,2048,128};
  const int Ns[8]  = {128,128,128,128,2048,2048,128,2048};
  const unsigned dsts[8] = {0,262144,524288,589824,655360,917504,1179648,1441792};
  int seg = 0;
  #pragma unroll
  for (int i = 0; i < 7; ++i) seg += (id >= cum[i+1]);
  int rel = id - cum[seg];
  int bx = rel & ((1 << gsh[seg]) - 1), by = rel >> gsh[seg];
  int K = Ks[seg], N = Ns[seg];
  const void* src = a.s[seg];
  u16* dst = wb + dsts[seg];
  int col0 = bx * 64, k0 = by * 64;
  int lr = t >> 4, lc = (t & 15) * 4;
  if (dt) {
    #pragma unroll
    for (int p = 0; p < 4; ++p) {
      int kr = lr + p * 16;
      float4 v = *(const float4*)((const float*)src + (size_t)(k0 + kr) * N + col0 + lc);
      Ts[kr][lc+0] = f2b(v.x); Ts[kr][lc+1] = f2b(v.y);
      Ts[kr][lc+2] = f2b(v.z); Ts[kr][lc+3] = f2b(v.w);
    }
  } else {
    #pragma unroll
    for (int p = 0; p < 4; ++p) {
      int kr = lr + p * 16;
      uint2 v = *(const uint2*)((const u16*)src + (size_t)(k0 + kr) * N + col0 + lc);
      *(uint2*)&Ts[kr][lc] = v;
    }
  }
  __syncthreads();
  int col = t >> 2, ks = (t & 3) * 16;
  u16 tmp[16];
  #pragma unroll
  for (int i = 0; i < 16; ++i) tmp[i] = Ts[ks + i][col];
  u16* dp = dst + (size_t)(col0 + col) * K + k0 + ks;
  *(uint4*)dp = *(uint4*)&tmp[0];
  *(uint4*)(dp + 8) = *(uint4*)&tmp[8];
}

// ---------- skinny GEMM body: C = A[M][K]*B, BT[N][K]; M-tile 16, N=JW*64 ----------
template<int JW>
__device__ __forceinline__ void skinny_body(const void* A, const u16* BT, u16* C0, u16* C1,
    int K, bool a32, int m0, int tid, u16 (*As)[40]) {
  int wave = tid >> 6, lane = tid & 63, quad = lane >> 4, l16 = lane & 15;
  f32x4 acc[JW];
  #pragma unroll
  for (int j = 0; j < JW; ++j) acc[j] = (f32x4){0.f,0.f,0.f,0.f};
  int row32 = tid >> 4, kp32 = (tid & 15) * 2;
  int row16 = tid >> 2, kp16 = (tid & 3) * 8;
  float2 pf32 = {};
  uint4 pf16 = {};
  if (a32) pf32 = *(const float2*)((const float*)A + (size_t)(m0+row32)*K + kp32);
  else if (tid < 64) pf16 = *(const uint4*)((const u16*)A + (size_t)(m0+row16)*K + kp16);
  uint4 bf[JW];
  #pragma unroll
  for (int j = 0; j < JW; ++j) {
    int col = wave*(JW*16) + j*16 + l16;
    bf[j] = *(const uint4*)(BT + (size_t)col*K + quad*8);
  }
  for (int k0 = 0; k0 < K; k0 += 32) {
    if (a32) { As[row32][kp32] = f2b(pf32.x); As[row32][kp32+1] = f2b(pf32.y); }
    else if (tid < 64) *(uint4*)&As[row16][kp16] = pf16;
    __syncthreads();
    int k1 = k0 + 32;
    uint4 bn[JW];
    if (k1 < K) {
      if (a32) pf32 = *(const float2*)((const float*)A + (size_t)(m0+row32)*K + k1 + kp32);
      else if (tid < 64) pf16 = *(const uint4*)((const u16*)A + (size_t)(m0+row16)*K + k1 + kp16);
      #pragma unroll
      for (int j = 0; j < JW; ++j) {
        int col = wave*(JW*16) + j*16 + l16;
        bn[j] = *(const uint4*)(BT + (size_t)col*K + k1 + quad*8);
      }
    }
    bf16x8 af = *(const bf16x8*)&As[l16][quad*8];
    #pragma unroll
    for (int j = 0; j < JW; ++j)
      acc[j] = __builtin_amdgcn_mfma_f32_16x16x32_bf16(af, __builtin_bit_cast(bf16x8, bf[j]), acc[j], 0, 0, 0);
    __syncthreads();
    #pragma unroll
    for (int j = 0; j < JW; ++j) bf[j] = bn[j];
  }
  #pragma unroll
  for (int j = 0; j < JW; ++j) {
    int col = wave*(JW*16) + j*16 + l16;
    u16* Cp = (col < 128) ? C0 : C1;
    int cc = col & 127;
    #pragma unroll
    for (int r = 0; r < 4; ++r)
      Cp[(size_t)(m0 + quad*4 + r)*128 + cc] = f2b(acc[j][r]);
  }
}

// ---------- up GEMM body: C[M][N] = A[M][128]*B, BT[N][128]; 64x64 tile ----------
__device__ __forceinline__ void gemm_up_body(const u16* A, const u16* BT, void* C, int ldc,
    bool o32, int m0, int n0, int tid, u16 (*As)[40]) {
  int wave = tid >> 6, lane = tid & 63, quad = lane >> 4, l16 = lane & 15;
  f32x4 acc[4] = {};
  int row = tid >> 2, kp = (tid & 3) * 8;
  uint4 pa = *(const uint4*)(A + (size_t)(m0+row)*128 + kp);
  uint4 bf[4];
  #pragma unroll
  for (int j = 0; j < 4; ++j)
    bf[j] = *(const uint4*)(BT + (size_t)(n0 + j*16 + l16)*128 + quad*8);
  #pragma unroll
  for (int k0 = 0; k0 < 128; k0 += 32) {
    *(uint4*)&As[row][kp] = pa;
    __syncthreads();
    uint4 bn[4];
    if (k0 < 96) {
      pa = *(const uint4*)(A + (size_t)(m0+row)*128 + k0 + 32 + kp);
      #pragma unroll
      for (int j = 0; j < 4; ++j)
        bn[j] = *(const uint4*)(BT + (size_t)(n0 + j*16 + l16)*128 + k0 + 32 + quad*8);
    }
    bf16x8 af = *(const bf16x8*)&As[wave*16 + l16][quad*8];
    #pragma unroll
    for (int j = 0; j < 4; ++j)
      acc[j] = __builtin_amdgcn_mfma_f32_16x16x32_bf16(af, __builtin_bit_cast(bf16x8, bf[j]), acc[j], 0, 0, 0);
    __syncthreads();
    #pragma unroll
    for (int j = 0; j < 4; ++j) bf[j] = bn[j];
  }
  #pragma unroll
  for (int j = 0; j < 4; ++j) {
    #pragma unroll
    for (int r = 0; r < 4; ++r) {
      size_t ci = (size_t)(m0 + wave*16 + quad*4 + r)*ldc + n0 + j*16 + l16;
      float v = acc[j][r];
      if (o32) ((float*)C)[ci] = v; else ((u16*)C)[ci] = f2b(v);
    }
  }
}

// ---------- k post body: RMSNorm+RoPE; kraw rows -> kT[(b*16+h)*1024+n][128] ----------
__device__ __forceinline__ void kpost_body(const u16* kraw, u16* kT, const u16* kw,
                                           const int* spos, int rel, int tid) {
  int wave = tid >> 6, lane = tid & 63;
  int rr = rel * 4 + wave;               // (b*1024+n)*16 + h
  int n = (rr >> 4) & 1023, b = rr >> 14, h = rr & 15;
  size_t base = (size_t)rr * 128;
  float x0 = b2f(kraw[base + lane]);
  float x1 = b2f(kraw[base + lane + 64]);
  float ss = wsum(x0*x0 + x1*x1);
  float inv = rsqrtf(ss * (1.0f/128.0f) + 1e-6f);
  float y0 = x0 * inv * b2f(kw[lane]);
  float y1 = x1 * inv * b2f(kw[lane + 64]);
  float pos = (float)spos[n];
  float invf = __expf(-(float)lane * (9.210340371976184f / 64.0f));
  float sn, cs; sincosf(pos * invf, &sn, &cs);
  size_t ob = ((size_t)(b*16 + h) * 1024 + n) * 128;
  kT[ob + lane]      = f2b(y0*cs - y1*sn);
  kT[ob + lane + 64] = f2b(y1*cs + y0*sn);
}

// ---------- V transpose body: vraw -> vtt[b,h,dh,n] (f16) ----------
__device__ __forceinline__ void vtrans_body(const u16* vraw, u16* vtt, int bid, int t,
                                            u16 (*Vs)[136]) {
  int ng = bid & 15, bh = bid >> 4;
  int b = bh >> 4, h = bh & 15;
  int n0 = ng * 64;
  int li = t >> 4, seg = (t & 15) * 8;
  #pragma unroll
  for (int p = 0; p < 4; ++p) {
    int i = li + p * 16;
    size_t row = (size_t)(b*1024 + n0 + i) * 16 + h;
    *(uint4*)&Vs[i][seg] = *(const uint4*)(vraw + row*128 + seg);
  }
  __syncthreads();
  int dh = t >> 1, nh = (t & 1) * 32;
  u16 outv[32];
  #pragma unroll
  for (int i = 0; i < 32; ++i) outv[i] = f2h(b2f(Vs[nh + i][dh]));
  u16* dst = vtt + ((size_t)bh * 128 + dh) * 1024 + n0 + nh;
  *(uint4*)(dst)      = *(uint4*)&outv[0];
  *(uint4*)(dst + 8)  = *(uint4*)&outv[8];
  *(uint4*)(dst + 16) = *(uint4*)&outv[16];
  *(uint4*)(dst + 24) = *(uint4*)&outv[24];
}

// ---------- merged launches ----------
__global__ __launch_bounds__(256)
void k_down_all(const void* x, const void* snap, const u16* BdT, const u16* BkvT,
                u16* qlat, u16* glat, u16* kraw, u16* vraw, const int* flag) {
  __shared__ u16 As[16][40];
  int id = blockIdx.x;
  bool a32 = flag[0] != 0;
  if (id < 256) skinny_body<4>(x, BdT, qlat, glat, 2048, a32, id*16, threadIdx.x, As);
  else          skinny_body<4>(snap, BkvT, kraw, vraw, 512, a32, (id-256)*16, threadIdx.x, As);
}

__global__ __launch_bounds__(256)
void k_mid_all(const u16* qlat, const u16* glat, const u16* WquT, const u16* WguT,
               u16* qraw, u16* graw, const u16* kraw, u16* kT, const u16* vraw, u16* vtt,
               const u16* ckw, const int* spos, const int* flag) {
  __shared__ u16 smem[64*136];
  int id = blockIdx.x, tid = threadIdx.x;
  if (id < 4096) {
    u16 (*As)[40] = (u16 (*)[40])smem;
    int rel = id & 2047;
    const u16* A  = (id < 2048) ? qlat : glat;
    const u16* BT = (id < 2048) ? WquT : WguT;
    u16* C        = (id < 2048) ? qraw : graw;
    gemm_up_body(A, BT, C, 2048, false, (rel >> 5) * 64, (rel & 31) * 64, tid, As);
  } else if (id < 12288) {
    kpost_body(kraw, kT, ckw, spos, id - 4096, tid);
  } else {
    vtrans_body(vraw, vtt, id - 12288, tid, (u16 (*)[136])smem);
  }
}

__global__ __launch_bounds__(256)
void k_olat(const u16* Ao, const u16* WodT, u16* olat, const int* flag) {
  __shared__ u16 As[16][40];
  skinny_body<2>(Ao, WodT, olat, olat, 2048, false, blockIdx.x*16, threadIdx.x, As);
}

__global__ __launch_bounds__(256)
void k_gemm_up(const u16* A, const u16* BT, void* C, int ldc, const int* flag, int out_dyn) {
  __shared__ u16 As[64][40];
  gemm_up_body(A, BT, C, ldc, out_dyn && flag[0], blockIdx.y*64, blockIdx.x*64, threadIdx.x, As);
}

// ---------- fused attention (q-norm fused, prefix-skip, ballot select) ----------
__global__ __launch_bounds__(256, 4)
void k_attn(const u16* qraw, const u16* kT, const u16* vtt, const u16* graw,
            const int* spos, const int* tok, const u16* sink, const u16* qw, u16* o) {
  __shared__ u16 sc[16][1032];        // scores/weights (f16)
  __shared__ int pos_s[1024];
  __shared__ float rz_s[16];
  u16 (*Qs)[136] = (u16 (*)[136])&sc[0][0];   // overlays sc rows 0..2 (transient)

  int tid = threadIdx.x;
  int wave = tid >> 6, lane = tid & 63, quad = lane >> 4, l16 = lane & 15;
  int bid = blockIdx.x;
  int tile = bid & 127, bh = bid >> 7;
  int h = bh & 15, b = bh >> 4;
  int t0 = tile * 16;
  int tok0 = tok[0];

  ((int4*)pos_s)[tid] = ((const int4*)spos)[tid];

  // fused q RMSNorm + RoPE into Qs (bitwise identical to old k_qpost)
  {
    float qw0 = b2f(qw[lane]), qw1 = b2f(qw[lane + 64]);
    float invf = __expf(-(float)lane * (9.210340371976184f / 64.0f));
    #pragma unroll 1
    for (int s = 0; s < 4; ++s) {
      int i = wave*4 + s;
      size_t base = ((size_t)(b*2048 + t0 + i))*2048 + h*128;
      float x0 = b2f(qraw[base + lane]);
      float x1 = b2f(qraw[base + lane + 64]);
      float ss = wsum(x0*x0 + x1*x1);
      float inv = rsqrtf(ss * (1.0f/128.0f) + 1e-6f);
      float y0 = x0 * inv * qw0;
      float y1 = x1 * inv * qw1;
      float pos = (float)(tok0 + t0 + i);
      float sn, cs; sincosf(pos * invf, &sn, &cs);
      Qs[i][lane]      = f2b(y0*cs - y1*sn);
      Qs[i][lane + 64] = f2b(y1*cs + y0*sn);
    }
  }
  __syncthreads();

  // prefix bound: positions sorted, column n relevant iff pos[n] < tok0+t0+15
  int nmax;
  {
    int lim = tok0 + t0 + 15;
    int lo = 0, hi = 1024;
    #pragma unroll 1
    while (lo < hi) { int mid = (lo + hi) >> 1; if (pos_s[mid] < lim) lo = mid + 1; else hi = mid; }
    nmax = lo;
  }
  int pmax = (nmax + 63) >> 6;
  int kkmax = (nmax + 31) >> 5;

  bf16x8 af[4];
  #pragma unroll
  for (int ks = 0; ks < 4; ++ks) af[ks] = *(const bf16x8*)&Qs[l16][ks*32 + quad*8];
  __syncthreads();   // protect Qs before sc writes

  // phase 1: scores for p < pmax; -inf fill beyond
  const u16* kTb = kT + (size_t)bh * 131072;
  int nrow = wave*16 + l16;
  uint4 kf[4];
  if (pmax > 0) {
    const u16* kr = kTb + (size_t)nrow * 128 + quad*8;
    #pragma unroll
    for (int ks = 0; ks < 4; ++ks) kf[ks] = *(const uint4*)(kr + ks*32);
  }
  #pragma unroll 1
  for (int p = 0; p < pmax; ++p) {
    uint4 kn[4];
    if (p + 1 < pmax) {
      const u16* kr = kTb + (size_t)((p+1)*64 + nrow) * 128 + quad*8;
      #pragma unroll
      for (int ks = 0; ks < 4; ++ks) kn[ks] = *(const uint4*)(kr + ks*32);
    }
    f32x4 c = {};
    #pragma unroll
    for (int ks = 0; ks < 4; ++ks)
      c = __builtin_amdgcn_mfma_f32_16x16x32_bf16(af[ks], __builtin_bit_cast(bf16x8, kf[ks]), c, 0, 0, 0);
    int n = p*64 + nrow;
    int pn = pos_s[n];
    #pragma unroll
    for (int r = 0; r < 4; ++r) {
      int t = quad*4 + r;
      float s = c[r] * 0.08838834764831845f;
      if (pn >= tok0 + t0 + t) s = -INFINITY;
      sc[t][n] = f2h(s);
    }
    #pragma unroll
    for (int ks = 0; ks < 4; ++ks) kf[ks] = kn[ks];
  }
  #pragma unroll 1
  for (int p = pmax; p < 16; ++p) {
    int n = p*64 + nrow;
    #pragma unroll
    for (int r = 0; r < 4; ++r) sc[quad*4 + r][n] = 0xFC00u;  // f16 -inf
  }
  __syncthreads();

  float sinkv = b2f(sink[h]);

  // phase 2: per-t top-64 threshold (ballot+popc) + softmax weights
  #pragma unroll 1
  for (int s5 = 0; s5 < 4; ++s5) {
    int tl = wave*4 + s5;
    uint4 r0 = *(const uint4*)&sc[tl][lane*16];
    uint4 r1 = *(const uint4*)&sc[tl][lane*16 + 8];
    float sv[16]; int key[16];
    float mx = -INFINITY;
    #pragma unroll
    for (int j = 0; j < 16; ++j) {
      u16 hb = (j < 8) ? ((const u16*)&r0)[j] : ((const u16*)&r1)[j-8];
      float f = h2f(hb);
      sv[j] = f; mx = fmaxf(mx, f);
      float fs = fminf(fmaxf(f * 256.0f + 2048.0f, 0.0f), 4095.0f);
      key[j] = (int)fs;
    }
    mx = wmax(mx);
    int lo = 0, hi = 4096;
    #pragma unroll 1
    for (int it = 0; it < 12; ++it) {
      int mid = (lo + hi) >> 1;
      int c = 0;
      #pragma unroll
      for (int j = 0; j < 16; ++j) c += (int)__popcll(__ballot(key[j] >= mid));
      if (c >= 64) lo = mid; else hi = mid;
    }
    float m = fmaxf(mx, sinkv);
    float zp = 0.f;
    u16 wq[16];
    #pragma unroll
    for (int j = 0; j < 16; ++j) {
      float e = (key[j] >= lo && sv[j] > -1e37f) ? __expf(sv[j] - m) : 0.f;
      zp += e;
      wq[j] = f2h(e);
    }
    float Z = wsum(zp) + __expf(sinkv - m);
    if (lane == 0) rz_s[tl] = 1.0f / Z;
    *(uint4*)&sc[tl][lane*16]     = *(uint4*)&wq[0];
    *(uint4*)&sc[tl][lane*16 + 8] = *(uint4*)&wq[8];
  }
  __syncthreads();

  // phase 3: dense PV via MFMA f16 over kk < kkmax (weights are exactly 0 beyond)
  const u16* vbase = vtt + (size_t)bh * 131072;
  int dh0 = wave * 32;
  const u16* vr0 = vbase + (size_t)(dh0 + l16)*1024 + quad*8;
  const u16* vr1 = vbase + (size_t)(dh0 + 16 + l16)*1024 + quad*8;
  f32x4 acc0 = {}, acc1 = {};
  uint4 vf0 = *(const uint4*)vr0;
  uint4 vf1 = *(const uint4*)vr1;
  #pragma unroll 1
  for (int kk = 0; kk < kkmax; ++kk) {
    uint4 vn0, vn1;
    if (kk + 1 < kkmax) {
      vn0 = *(const uint4*)(vr0 + (kk+1)*32);
      vn1 = *(const uint4*)(vr1 + (kk+1)*32);
    }
    f16x8 a = *(const f16x8*)&sc[l16][kk*32 + quad*8];
    acc0 = __builtin_amdgcn_mfma_f32_16x16x32_f16(a, __builtin_bit_cast(f16x8, vf0), acc0, 0, 0, 0);
    acc1 = __builtin_amdgcn_mfma_f32_16x16x32_f16(a, __builtin_bit_cast(f16x8, vf1), acc1, 0, 0, 0);
    vf0 = vn0; vf1 = vn1;
  }

  // epilogue: *1/Z, *sigmoid(gate), store (o aliases graw; same-thread RaW only)
  #pragma unroll
  for (int r = 0; r < 4; ++r) {
    int t = quad*4 + r;
    float rz = rz_s[t];
    size_t oi = ((size_t)(b*2048 + t0 + t))*2048 + h*128 + dh0 + l16;
    float g0 = 1.0f / (1.0f + __expf(-b2f(graw[oi])));
    float g1 = 1.0f / (1.0f + __expf(-b2f(graw[oi + 16])));
    o[oi] = f2b(acc0[r] * rz * g0);
    o[oi + 16] = f2b(acc1[r] * rz * g1);
  }
}

extern "C" void kernel_launch(void* const* d_in, const int* in_sizes, int n_in,
                              void* d_out, int out_size, void* d_ws, size_t ws_size,
                              hipStream_t stream) {
  char* ws = (char*)d_ws;
  int* flag = (int*)(ws + 0);
  u16* wb = (u16*)(ws + 4096);

  // wb element offsets
  u16* BdT  = wb + 0;        // [256][2048]
  u16* BkvT = wb + 524288;   // [256][512]
  u16* WquT = wb + 655360;   // [2048][128]
  u16* WguT = wb + 917504;   // [2048][128]
  u16* WodT = wb + 1179648;  // [128][2048]
  u16* WouT = wb + 1441792;  // [2048][128]
  u16* cqw  = wb + 1703936;
  u16* ckw  = wb + 1704064;
  u16* csink= wb + 1704192;

  // byte offsets
  const size_t O_QLAT = 4198400;    // [4096][128] bf16 (olat aliases later)
  const size_t O_GLAT = 5246976;    // [4096][128] bf16
  const size_t O_QRAW = 6295552;    // [4096][2048] bf16 (RAW q; norm fused in attn)
  const size_t O_GRAW = 23072768;   // [4096][2048] bf16 (attn writes out in-place)
  const size_t O_KRAW = 39849984;   // [32768][128] bf16
  const size_t O_VRAW = 48238592;   // [32768][128] bf16
  const size_t O_KT   = 56627200;   // [32][1024][128] bf16
  const size_t O_VTT  = 65015808;   // [32][128][1024] f16

  const int* spos = (const int*)d_in[2];
  const int* tok  = (const int*)d_in[3];

  k_detect<<<1, 64, 0, stream>>>((const u32*)d_in[0], flag);

  WtArgs wa;
  wa.s[0] = d_in[4];  wa.s[1] = d_in[6];  wa.s[2] = d_in[10]; wa.s[3] = d_in[11];
  wa.s[4] = d_in[5];  wa.s[5] = d_in[7];  wa.s[6] = d_in[8];  wa.s[7] = d_in[9];
  wa.vq = d_in[12]; wa.vk = d_in[13]; wa.vs = d_in[14];
  k_wtrans_all<<<417, 256, 0, stream>>>(wa, wb, flag);

  k_down_all<<<2304, 256, 0, stream>>>(d_in[0], d_in[1], BdT, BkvT,
      (u16*)(ws + O_QLAT), (u16*)(ws + O_GLAT), (u16*)(ws + O_KRAW), (u16*)(ws + O_VRAW), flag);

  k_mid_all<<<12800, 256, 0, stream>>>((const u16*)(ws + O_QLAT), (const u16*)(ws + O_GLAT),
      WquT, WguT, (u16*)(ws + O_QRAW), (u16*)(ws + O_GRAW),
      (const u16*)(ws + O_KRAW), (u16*)(ws + O_KT), (const u16*)(ws + O_VRAW), (u16*)(ws + O_VTT),
      ckw, spos, flag);

  k_attn<<<4096, 256, 0, stream>>>((const u16*)(ws + O_QRAW), (const u16*)(ws + O_KT),
      (const u16*)(ws + O_VTT), (const u16*)(ws + O_GRAW), spos, tok, csink, cqw,
      (u16*)(ws + O_GRAW));

  k_olat<<<256, 256, 0, stream>>>((const u16*)(ws + O_GRAW), WodT, (u16*)(ws + O_QLAT), flag);
  k_gemm_up<<<dim3(32,64), 256, 0, stream>>>((const u16*)(ws + O_QLAT), WouT, d_out, 2048, flag, 1);
}